// Round 1
// baseline (10192.358 us; speedup 1.0000x reference)
//
#include <hip/hip_runtime.h>

// Problem constants
#define B_    64
#define C_    4096
#define T_ALL 72
#define T_H   24
#define T_FC  48
#define F_IN  8
#define HID   64
#define NSEQ  (B_ * C_)   // 262144

// ---------------------------------------------------------------------------
// Setup: fold fc_in into W_ih.
//   Wc[j][i] = sum_k W_ih[j][k] * W_in[k][i]   (192 x 4)
//   bc[j]    = b_ih[j] + sum_k W_ih[j][k] * b_in[k]
// ws layout: [0..767] Wc row-major, [768..959] bc
// ---------------------------------------------------------------------------
__global__ __launch_bounds__(192) void setup_kernel(
    const float* __restrict__ W_in, const float* __restrict__ b_in,
    const float* __restrict__ W_ih, const float* __restrict__ b_ih,
    float* __restrict__ ws) {
  int j = threadIdx.x;  // 0..191
  float a0 = 0.f, a1 = 0.f, a2 = 0.f, a3 = 0.f, ab = 0.f;
  for (int k = 0; k < HID; ++k) {
    float w = W_ih[j * HID + k];
    a0 += w * W_in[k * 4 + 0];
    a1 += w * W_in[k * 4 + 1];
    a2 += w * W_in[k * 4 + 2];
    a3 += w * W_in[k * 4 + 3];
    ab += w * b_in[k];
  }
  ws[j * 4 + 0] = a0;
  ws[j * 4 + 1] = a1;
  ws[j * 4 + 2] = a2;
  ws[j * 4 + 3] = a3;
  ws[768 + j] = ab + b_ih[j];
}

// Fast activations: single v_exp_f32 + v_rcp_f32 (~1 ulp, fine vs 2.9e-2 tol)
__device__ __forceinline__ float fast_sigmoid(float x) {
  float e = __builtin_amdgcn_exp2f(-1.4426950408889634f * x);
  return __builtin_amdgcn_rcpf(1.0f + e);
}
// tanh(x) = 2*sigmoid(2x) - 1  (no overflow/NaN at large |x|)
__device__ __forceinline__ float fast_tanh(float x) {
  float e = __builtin_amdgcn_exp2f(-2.8853900817779268f * x);
  return 2.0f * __builtin_amdgcn_rcpf(1.0f + e) - 1.0f;
}

// ---------------------------------------------------------------------------
// Main persistent GRU: one thread = one (b,c) sequence, all 48 steps.
// h[64] + hn[64] in registers; W_hh + fused input weights in LDS (uniform
// broadcast reads).
// ---------------------------------------------------------------------------
__global__ __launch_bounds__(256) void gru_kernel(
    const float* __restrict__ X, const float* __restrict__ H,
    const float* __restrict__ xn, const float* __restrict__ W_hh,
    const float* __restrict__ b_hh, const float* __restrict__ W_out,
    const float* __restrict__ b_out, const float* __restrict__ ws,
    float* __restrict__ out) {
  __shared__ float sW[192 * 64];   // W_hh row-major: rows 0..63 r, 64..127 z, 128..191 n
  __shared__ float sWc[192 * 4];   // fused input weights
  __shared__ float sbc[192];       // fused input bias
  __shared__ float sbh[192];       // b_hh
  __shared__ float sWo[64];        // W_out

  const int tid = threadIdx.x;
  for (int i = tid; i < 192 * 64; i += 256) sW[i] = W_hh[i];
  for (int i = tid; i < 768; i += 256) sWc[i] = ws[i];
  if (tid < 192) {
    sbc[tid] = ws[768 + tid];
    sbh[tid] = b_hh[tid];
  }
  if (tid < 64) sWo[tid] = W_out[tid];
  __syncthreads();

  const int s = blockIdx.x * 256 + tid;  // sequence id = b*C + c
  const int b = s >> 12;                 // / 4096
  const int c = s & 4095;

  float h[HID];
  const float4* Hp = reinterpret_cast<const float4*>(H + (size_t)s * HID);
#pragma unroll
  for (int k = 0; k < HID / 4; ++k) {
    float4 v = Hp[k];
    h[4 * k + 0] = v.x;
    h[4 * k + 1] = v.y;
    h[4 * k + 2] = v.z;
    h[4 * k + 3] = v.w;
  }
  float xp = xn[s];

  // X[b, 24+t, c, 5..7]
  const float* Xp = X + (((size_t)b * T_ALL + T_H) * C_ + c) * F_IN + 5;
  float* Op = out + (size_t)b * (T_FC * C_) + c;
  const float bo = b_out[0];

  const float4* sW4 = reinterpret_cast<const float4*>(sW);

#pragma unroll 1
  for (int t = 0; t < T_FC; ++t) {
    const float x1 = Xp[0];
    const float x2 = Xp[1];
    const float x3 = Xp[2];
    Xp += C_ * F_IN;

    float hn[HID];
    float o = bo;
#pragma unroll
    for (int u = 0; u < HID; ++u) {
      float gr = sbh[u];
      float gz = sbh[64 + u];
      float gn = sbh[128 + u];
#pragma unroll
      for (int k4 = 0; k4 < HID / 4; ++k4) {
        float4 wr = sW4[u * 16 + k4];
        float4 wz = sW4[(64 + u) * 16 + k4];
        float4 wn = sW4[(128 + u) * 16 + k4];
        gr += h[4 * k4 + 0] * wr.x + h[4 * k4 + 1] * wr.y +
              h[4 * k4 + 2] * wr.z + h[4 * k4 + 3] * wr.w;
        gz += h[4 * k4 + 0] * wz.x + h[4 * k4 + 1] * wz.y +
              h[4 * k4 + 2] * wz.z + h[4 * k4 + 3] * wz.w;
        gn += h[4 * k4 + 0] * wn.x + h[4 * k4 + 1] * wn.y +
              h[4 * k4 + 2] * wn.z + h[4 * k4 + 3] * wn.w;
      }
      float ir = sbc[u] + xp * sWc[4 * u + 0] + x1 * sWc[4 * u + 1] +
                 x2 * sWc[4 * u + 2] + x3 * sWc[4 * u + 3];
      float iz = sbc[64 + u] + xp * sWc[4 * (64 + u) + 0] +
                 x1 * sWc[4 * (64 + u) + 1] + x2 * sWc[4 * (64 + u) + 2] +
                 x3 * sWc[4 * (64 + u) + 3];
      float in_ = sbc[128 + u] + xp * sWc[4 * (128 + u) + 0] +
                  x1 * sWc[4 * (128 + u) + 1] + x2 * sWc[4 * (128 + u) + 2] +
                  x3 * sWc[4 * (128 + u) + 3];
      float r = fast_sigmoid(ir + gr);
      float z = fast_sigmoid(iz + gz);
      float n = fast_tanh(in_ + r * gn);
      float hu = (1.0f - z) * n + z * h[u];
      hn[u] = hu;
      o += hu * sWo[u];
    }
#pragma unroll
    for (int k = 0; k < HID; ++k) h[k] = hn[k];
    *Op = o;
    Op += C_;
    xp = o;  // feedback: x_prev = this step's prediction
  }
}

extern "C" void kernel_launch(void* const* d_in, const int* in_sizes, int n_in,
                              void* d_out, int out_size, void* d_ws,
                              size_t ws_size, hipStream_t stream) {
  const float* X     = (const float*)d_in[0];
  const float* H     = (const float*)d_in[1];
  const float* xn    = (const float*)d_in[2];
  const float* W_in  = (const float*)d_in[3];
  const float* b_in  = (const float*)d_in[4];
  const float* W_ih  = (const float*)d_in[5];
  const float* W_hh  = (const float*)d_in[6];
  const float* b_ih  = (const float*)d_in[7];
  const float* b_hh  = (const float*)d_in[8];
  const float* W_out = (const float*)d_in[9];
  const float* b_out = (const float*)d_in[10];
  float* out = (float*)d_out;
  float* ws  = (float*)d_ws;

  setup_kernel<<<1, 192, 0, stream>>>(W_in, b_in, W_ih, b_ih, ws);
  gru_kernel<<<NSEQ / 256, 256, 0, stream>>>(X, H, xn, W_hh, b_hh, W_out,
                                             b_out, ws, out);
}